// Round 2
// baseline (41.608 us; speedup 1.0000x reference)
//
#include <hip/hip_runtime.h>

// ContrastiveLoss collapses to:
//   v = sum_i mask_i * latent_i / max(||latent_i||, eps)   (64-vector)
//   out = COF1 * (||v||^2 - sum(mask)) / (2N)
// O(N*d). Bottleneck is latency, not bandwidth -> maximize wave count.

#define EPSV 1e-8f
#define COF1 0.01f

constexpr int N_ROWS = 8192;
constexpr int DIM = 64;
constexpr int TPB = 256;
constexpr int WAVES_PER_BLOCK = TPB / 64;                 // 4
constexpr int BLOCKS = 512;                               // 2048 waves total
constexpr int ROWS_PER_WAVE = N_ROWS / (BLOCKS * WAVES_PER_BLOCK);  // 4
constexpr int SLOT = DIM + 1;                             // v[64] + count

// Kernel 1: each wave handles 4 rows (lane = column, coalesced 256B loads).
// All 4 rows loaded up-front so HBM latency overlaps the shuffle chains.
// Block reduces its 4 waves via LDS -> one 65-float partial per block.
__global__ __launch_bounds__(TPB, 2) void cl_partial(const float* __restrict__ latent,
                                                     float* __restrict__ ws) {
    const int wv   = threadIdx.x >> 6;
    const int lane = threadIdx.x & 63;
    const int row0 = (blockIdx.x * WAVES_PER_BLOCK + wv) * ROWS_PER_WAVE;

    float x[ROWS_PER_WAVE];
    #pragma unroll
    for (int r = 0; r < ROWS_PER_WAVE; ++r)
        x[r] = latent[(row0 + r) * DIM + lane];

    float v = 0.0f, cnt = 0.0f;
    #pragma unroll
    for (int r = 0; r < ROWS_PER_WAVE; ++r) {
        float s = x[r];
        float q = x[r] * x[r];
        #pragma unroll
        for (int off = 32; off; off >>= 1) {
            s += __shfl_xor(s, off);
            q += __shfl_xor(q, off);
        }
        if (s != 0.0f) {
            v += x[r] * (1.0f / fmaxf(sqrtf(q), EPSV));
            cnt += 1.0f;
        }
    }

    __shared__ float sv[WAVES_PER_BLOCK][SLOT];
    sv[wv][lane] = v;
    if (lane == 0) sv[wv][DIM] = cnt;
    __syncthreads();

    if (wv == 0) {
        float a = sv[0][lane] + sv[1][lane] + sv[2][lane] + sv[3][lane];
        float* slot = ws + blockIdx.x * SLOT;
        slot[lane] = a;
        if (lane == 0)
            slot[DIM] = sv[0][DIM] + sv[1][DIM] + sv[2][DIM] + sv[3][DIM];
    }
}

// Kernel 2: 4 waves stride the 512 block partials, LDS-combine, finalize.
__global__ __launch_bounds__(256) void cl_final(const float* __restrict__ ws,
                                                float* __restrict__ out) {
    const int wv   = threadIdx.x >> 6;
    const int lane = threadIdx.x & 63;

    float acc = 0.0f, c = 0.0f;
    for (int b = wv; b < BLOCKS; b += WAVES_PER_BLOCK) {
        acc += ws[b * SLOT + lane];
        c   += ws[b * SLOT + DIM];
    }

    __shared__ float sv[WAVES_PER_BLOCK][SLOT];
    sv[wv][lane] = acc;
    if (lane == 0) sv[wv][DIM] = c;
    __syncthreads();

    if (wv == 0) {
        float a = sv[0][lane] + sv[1][lane] + sv[2][lane] + sv[3][lane];
        float d = a * a;
        #pragma unroll
        for (int off = 32; off; off >>= 1)
            d += __shfl_xor(d, off);
        if (lane == 0) {
            float ctot = sv[0][DIM] + sv[1][DIM] + sv[2][DIM] + sv[3][DIM];
            out[0] = COF1 * (d - ctot) / (2.0f * (float)N_ROWS);
        }
    }
}

extern "C" void kernel_launch(void* const* d_in, const int* in_sizes, int n_in,
                              void* d_out, int out_size, void* d_ws, size_t ws_size,
                              hipStream_t stream) {
    const float* latent = (const float*)d_in[0];
    float* out = (float*)d_out;
    float* ws = (float*)d_ws;   // needs 512*65*4 = 133,120 bytes

    cl_partial<<<BLOCKS, TPB, 0, stream>>>(latent, ws);
    cl_final<<<1, 256, 0, stream>>>(ws, out);
}

// Round 3
// 12.672 us; speedup vs baseline: 3.2836x; 3.2836x over previous
//
#include <hip/hip_runtime.h>

// ContrastiveLoss collapses to:
//   v = sum_i mask_i * latent_i / max(||latent_i||, eps)   (64-vector)
//   out = COF1 * (||v||^2 - sum(mask)) / (2N)
// O(N*d). Kernel work ~2 MB read; measurement appears floored by the
// harness's 256 MiB d_ws poison fill (~39 us @ 6.9 TB/s). This round:
// make both kernels unambiguously tiny to confirm that floor.

#define EPSV 1e-8f
#define COF1 0.01f

constexpr int N_ROWS = 8192;
constexpr int DIM = 64;
constexpr int TPB = 256;
constexpr int WAVES_PER_BLOCK = TPB / 64;            // 4
constexpr int BLOCKS = 256;                          // 1024 waves, 1 block/CU
constexpr int ROWS_PER_WAVE = N_ROWS / (BLOCKS * WAVES_PER_BLOCK);  // 8
constexpr int SLOT = 68;                             // v[64] + cnt + pad (16B aligned)

// Kernel 1: float4 loads — one wave covers 4 rows per 1 KB load batch.
// lane L: row-group g = L>>4, column quad c4 = L&15 (cols 4*c4..4*c4+3).
// Row sum/sumsq reduced over the 16-lane group; cross-group v combine via
// shfl_xor(16|32); 4 waves combined in LDS -> one 68-float slot per block.
__global__ __launch_bounds__(TPB, 2) void cl_partial(const float* __restrict__ latent,
                                                     float* __restrict__ ws) {
    const int wv   = threadIdx.x >> 6;
    const int lane = threadIdx.x & 63;
    const int g    = lane >> 4;     // row within batch
    const int c4   = lane & 15;     // column quad
    const int row0 = (blockIdx.x * WAVES_PER_BLOCK + wv) * ROWS_PER_WAVE;

    const float4* lat4 = (const float4*)latent;

    float4 v = make_float4(0.f, 0.f, 0.f, 0.f);
    float cnt = 0.0f;

    #pragma unroll
    for (int b = 0; b < ROWS_PER_WAVE / 4; ++b) {
        const int row = row0 + b * 4 + g;
        float4 x = lat4[row * (DIM / 4) + c4];

        float s = x.x + x.y + x.z + x.w;
        float q = x.x * x.x + x.y * x.y + x.z * x.z + x.w * x.w;
        #pragma unroll
        for (int off = 8; off; off >>= 1) {   // reduce within 16-lane group
            s += __shfl_xor(s, off);
            q += __shfl_xor(q, off);
        }
        if (s != 0.0f) {
            float inv = 1.0f / fmaxf(sqrtf(q), EPSV);
            v.x += x.x * inv; v.y += x.y * inv;
            v.z += x.z * inv; v.w += x.w * inv;
            if (c4 == 0) cnt += 1.0f;         // one count per row
        }
    }

    // combine the 4 row-groups (lanes with equal c4) via xor 16, 32
    #pragma unroll
    for (int off = 16; off <= 32; off <<= 1) {
        v.x += __shfl_xor(v.x, off); v.y += __shfl_xor(v.y, off);
        v.z += __shfl_xor(v.z, off); v.w += __shfl_xor(v.w, off);
        cnt += __shfl_xor(cnt, off);
    }
    // lanes 0..15 now hold final v[4*c4 .. 4*c4+3]; lane 0 holds wave cnt

    __shared__ float4 sv4[WAVES_PER_BLOCK][16];
    __shared__ float  scnt[WAVES_PER_BLOCK];
    if (lane < 16) sv4[wv][c4] = v;
    if (lane == 0) scnt[wv] = cnt;
    __syncthreads();

    if (wv == 0 && lane < 16) {
        float4 a = sv4[0][c4];
        float4 b1 = sv4[1][c4], b2 = sv4[2][c4], b3 = sv4[3][c4];
        a.x += b1.x + b2.x + b3.x; a.y += b1.y + b2.y + b3.y;
        a.z += b1.z + b2.z + b3.z; a.w += b1.w + b2.w + b3.w;
        ((float4*)(ws + blockIdx.x * SLOT))[c4] = a;
        if (lane == 0)
            ws[blockIdx.x * SLOT + 64] = scnt[0] + scnt[1] + scnt[2] + scnt[3];
    }
}

// Kernel 2: 4 waves x 64 slots each, 8-deep pipelined loads, LDS combine.
__global__ __launch_bounds__(256) void cl_final(const float* __restrict__ ws,
                                                float* __restrict__ out) {
    const int wv   = threadIdx.x >> 6;
    const int lane = threadIdx.x & 63;

    const float* base = ws + (wv * 64) * SLOT;
    float acc = 0.0f, c = 0.0f;
    for (int b0 = 0; b0 < 64; b0 += 8) {
        float t[8], tc[8];
        #pragma unroll
        for (int j = 0; j < 8; ++j) {         // 16 independent loads in flight
            t[j]  = base[(b0 + j) * SLOT + lane];
            tc[j] = base[(b0 + j) * SLOT + 64];
        }
        #pragma unroll
        for (int j = 0; j < 8; ++j) { acc += t[j]; c += tc[j]; }
    }

    __shared__ float sv[WAVES_PER_BLOCK][64];
    __shared__ float scnt[WAVES_PER_BLOCK];
    sv[wv][lane] = acc;
    if (lane == 0) scnt[wv] = c;
    __syncthreads();

    if (wv == 0) {
        float a = sv[0][lane] + sv[1][lane] + sv[2][lane] + sv[3][lane];
        float d = a * a;
        #pragma unroll
        for (int off = 32; off; off >>= 1)
            d += __shfl_xor(d, off);
        if (lane == 0) {
            float ctot = scnt[0] + scnt[1] + scnt[2] + scnt[3];
            out[0] = COF1 * (d - ctot) / (2.0f * (float)N_ROWS);
        }
    }
}

extern "C" void kernel_launch(void* const* d_in, const int* in_sizes, int n_in,
                              void* d_out, int out_size, void* d_ws, size_t ws_size,
                              hipStream_t stream) {
    const float* latent = (const float*)d_in[0];
    float* out = (float*)d_out;
    float* ws = (float*)d_ws;   // needs 256*68*4 = 69,632 bytes

    cl_partial<<<BLOCKS, TPB, 0, stream>>>(latent, ws);
    cl_final<<<1, 256, 0, stream>>>(ws, out);
}